// Round 1
// baseline (143.930 us; speedup 1.0000x reference)
//
#include <hip/hip_runtime.h>

// Degrade: per-sample depthwise 13x13 cross-correlation, stride 4,
// replicate padding p=6.  im: [8,4,1024,1024] f32, kernel: [8,1,13,13] f32,
// out: [8,4,256,256] f32.
//
// out[p][oy][ox] = sum_{ky,kx} im[p][clamp(4*oy+ky-6)][clamp(4*ox+kx-6)] * k[b][ky][kx]
//
// Memory-bound (136 MB @ ~6.3 TB/s ~= 22 us floor).  Each thread computes a
// 4x4 output tile so the 25x25 input patch (625 loads) serves 16 outputs
// (2704 FMAs) -- 4.3x load-traffic reduction vs 1 output/thread, keeping L2
// traffic (~330 MB) under the HBM floor.  Kernel weights in LDS (uniform
// broadcast reads).  float4 coalesced stores.

#define KS 13
#define PAD 6
#define STR 4
#define IH 1024
#define IW 1024
#define OH 256
#define OW 256

__global__ __launch_bounds__(256) void degrade_kernel(
    const float* __restrict__ im,
    const float* __restrict__ kern,
    float* __restrict__ out)
{
    const int plane = blockIdx.z;       // b*4 + c
    const int b     = plane >> 2;
    const int tid   = threadIdx.x;
    const int tx    = tid & 15;         // 16 threads across x
    const int ty    = tid >> 4;         // 16 threads across y
    const int OX0   = blockIdx.x * 64;  // block output tile: 64 x 64
    const int OY0   = blockIdx.y * 64;

    __shared__ float sk[KS * KS];
    if (tid < KS * KS) sk[tid] = kern[b * KS * KS + tid];
    __syncthreads();

    const float* __restrict__ pl = im + (size_t)plane * (IH * IW);

    // Per-thread clamped column offsets (computed once; stays in registers --
    // all indexing below is compile-time constant after unrolling).
    int cof[25];
    const int gx0 = OX0 * STR + 16 * tx - PAD;
#pragma unroll
    for (int u = 0; u < 25; ++u) {
        int gx = gx0 + u;
        cof[u] = min(max(gx, 0), IW - 1);
    }

    float acc[4][4];
#pragma unroll
    for (int j = 0; j < 4; ++j)
#pragma unroll
        for (int i = 0; i < 4; ++i) acc[j][i] = 0.0f;

    const int gy0 = OY0 * STR + 16 * ty - PAD;

    // 25 input rows feed this thread's 4 output rows (rows reused across j
    // in registers).  t = 4*j + ky.
    for (int t = 0; t < 25; ++t) {
        const int gy = min(max(gy0 + t, 0), IH - 1);
        const float* __restrict__ row = pl + (size_t)gy * IW;

        float v[25];
#pragma unroll
        for (int u = 0; u < 25; ++u) v[u] = row[cof[u]];

#pragma unroll
        for (int j = 0; j < 4; ++j) {
            const int ky = t - STR * j;
            if (ky >= 0 && ky < KS) {       // wave-uniform branch
                const float* krow = &sk[ky * KS];
#pragma unroll
                for (int kx = 0; kx < KS; ++kx) {
                    const float kv = krow[kx];
#pragma unroll
                    for (int i = 0; i < 4; ++i)
                        acc[j][i] = fmaf(v[STR * i + kx], kv, acc[j][i]);
                }
            }
        }
    }

#pragma unroll
    for (int j = 0; j < 4; ++j) {
        const int oy = OY0 + 4 * ty + j;
        float4 val = make_float4(acc[j][0], acc[j][1], acc[j][2], acc[j][3]);
        *(float4*)(out + ((size_t)plane * OH + oy) * OW + OX0 + 4 * tx) = val;
    }
}

extern "C" void kernel_launch(void* const* d_in, const int* in_sizes, int n_in,
                              void* d_out, int out_size, void* d_ws, size_t ws_size,
                              hipStream_t stream)
{
    const float* im   = (const float*)d_in[0];
    const float* kern = (const float*)d_in[1];
    float* out        = (float*)d_out;

    dim3 grid(OW / 64, OH / 64, 32);   // 4 x 4 x 32 = 512 blocks
    degrade_kernel<<<grid, 256, 0, stream>>>(im, kern, out);
}

// Round 2
// 56.152 us; speedup vs baseline: 2.5632x; 2.5632x over previous
//
#include <hip/hip_runtime.h>

// Degrade: per-sample depthwise 13x13 cross-correlation, stride 4,
// replicate padding p=6.  im: [8,4,1024,1024] f32, kernel: [8,1,13,13] f32,
// out: [8,4,256,256] f32.
//
// R1: latency/gather-bound fix.
//  - per-thread tile 4 wide x 2 tall; block covers 64x32 outputs ->
//    grid (4,8,32)=1024 blocks = 4 blocks/CU (occupancy 2x vs R0).
//  - per-thread input window is misaligned by a COMPILE-TIME constant
//    (gx0 = 4*OX0+16*tx-6 === 2 mod 4), so the aligned 28-float window
//    is exactly 7 aligned float4 loads -> 3.5x fewer gather instrs than
//    25 scalar dwords.  Border lanes fall back to scalar clamped loads.
//  - kernel weights in LDS padded to 16 floats/row -> 4 ds_read_b128
//    broadcasts per ky-row (uniform addr, conflict-free).

#define KS 13
#define PAD 6
#define STR 4
#define IH 1024
#define IW 1024
#define OH 256
#define OW 256
#define TH 2          // output rows per thread
#define SPAN 28       // aligned float window per input row (7 x float4)

__global__ __launch_bounds__(256) void degrade_kernel(
    const float* __restrict__ im,
    const float* __restrict__ kern,
    float* __restrict__ out)
{
    const int plane = blockIdx.z;       // b*4 + c
    const int b     = plane >> 2;
    const int tid   = threadIdx.x;
    const int tx    = tid & 15;         // 16 threads across x (4 outputs each)
    const int ty    = tid >> 4;         // 16 threads across y (2 outputs each)
    const int OX0   = blockIdx.x * 64;
    const int OY0   = blockIdx.y * 32;

    // kernel weights, rows padded to 16 floats for aligned b128 reads
    __shared__ float sk[KS][16];
    if (tid < KS * 16) {
        int r = tid >> 4, c = tid & 15;
        sk[r][c] = (c < KS) ? kern[b * KS * KS + r * KS + c] : 0.0f;
    }
    __syncthreads();

    const float* __restrict__ pl = im + (size_t)plane * (IH * IW);

    // aligned window start: gx0 - 2 (gx0 === 2 mod 4 always)
    const int abase    = 4 * OX0 + 16 * tx - 8;
    const bool interior = (abase >= 0) && (abase + SPAN <= IW);
    const int gy0      = (OY0 + TH * ty) * STR - PAD;

    float acc[TH][4];
#pragma unroll
    for (int j = 0; j < TH; ++j)
#pragma unroll
        for (int i = 0; i < 4; ++i) acc[j][i] = 0.0f;

    // rows feeding this thread's TH output rows: t = 4*j + ky
    for (int t = 0; t < STR * TH + 9; ++t) {
        const int gy = min(max(gy0 + t, 0), IH - 1);
        const float* __restrict__ row = pl + (size_t)gy * IW;

        float v[SPAN];
        if (interior) {
            const float4* __restrict__ rp = (const float4*)(row + abase);
#pragma unroll
            for (int q = 0; q < SPAN / 4; ++q) {
                float4 x = rp[q];
                v[4 * q + 0] = x.x; v[4 * q + 1] = x.y;
                v[4 * q + 2] = x.z; v[4 * q + 3] = x.w;
            }
        } else {
#pragma unroll
            for (int u = 0; u < SPAN; ++u)
                v[u] = row[min(max(abase + u, 0), IW - 1)];
        }

#pragma unroll
        for (int j = 0; j < TH; ++j) {
            const int ky = t - STR * j;
            if (ky >= 0 && ky < KS) {           // wave-uniform per (t,j)
                float4 k0 = *(const float4*)&sk[ky][0];
                float4 k1 = *(const float4*)&sk[ky][4];
                float4 k2 = *(const float4*)&sk[ky][8];
                float4 k3 = *(const float4*)&sk[ky][12];
                float kr[KS] = {k0.x, k0.y, k0.z, k0.w,
                                k1.x, k1.y, k1.z, k1.w,
                                k2.x, k2.y, k2.z, k2.w, k3.x};
#pragma unroll
                for (int kx = 0; kx < KS; ++kx)
#pragma unroll
                    for (int i = 0; i < 4; ++i)
                        acc[j][i] = fmaf(v[2 + 4 * i + kx], kr[kx], acc[j][i]);
            }
        }
    }

#pragma unroll
    for (int j = 0; j < TH; ++j) {
        const int oy = OY0 + TH * ty + j;
        *(float4*)(out + ((size_t)plane * OH + oy) * OW + OX0 + 4 * tx) =
            make_float4(acc[j][0], acc[j][1], acc[j][2], acc[j][3]);
    }
}

extern "C" void kernel_launch(void* const* d_in, const int* in_sizes, int n_in,
                              void* d_out, int out_size, void* d_ws, size_t ws_size,
                              hipStream_t stream)
{
    const float* im   = (const float*)d_in[0];
    const float* kern = (const float*)d_in[1];
    float* out        = (float*)d_out;

    dim3 grid(OW / 64, OH / 32, 32);   // 4 x 8 x 32 = 1024 blocks
    degrade_kernel<<<grid, 256, 0, stream>>>(im, kern, out);
}